// Round 2
// baseline (497.321 us; speedup 1.0000x reference)
//
#include <hip/hip_runtime.h>
#include <math.h>

#define B_ 128
#define NTOK 577
#define P_ 576
#define D_ 768
#define G_ 17
#define KOCC 10
#define INV_TEMP 10.0f

// ws layout (floats):
//   sim    : [B_][P_]  @ 0
//   mask   : [B_][P_]  @ B_*P_
//   clsinv : [B_]      @ 2*B_*P_

__device__ __forceinline__ float dot4(float4 a, float4 b) {
    return fmaf(a.x, b.x, fmaf(a.y, b.y, fmaf(a.z, b.z, a.w * b.w)));
}

// K0: per batch: feats[b][0][:] = cls, zero feats[b][1..17][:], clsinv[b] = 1/max(||cls||,1e-12)
__global__ __launch_bounds__(256) void k0_cls(const float* __restrict__ x,
                                              float* __restrict__ feats,
                                              float* __restrict__ clsinv) {
    int b = blockIdx.x;
    const float* cls = x + (size_t)b * NTOK * D_;
    float* fb = feats + (size_t)b * 18 * D_;
    float ss = 0.f;
    for (int d = threadIdx.x; d < D_; d += 256) {
        float v = cls[d];
        fb[d] = v;
        ss = fmaf(v, v, ss);
    }
    for (int i = threadIdx.x; i < G_ * D_; i += 256) fb[D_ + i] = 0.f;
    #pragma unroll
    for (int off = 32; off; off >>= 1) ss += __shfl_xor(ss, off, 64);
    __shared__ float red[4];
    int wave = threadIdx.x >> 6, lane = threadIdx.x & 63;
    if (lane == 0) red[wave] = ss;
    __syncthreads();
    if (threadIdx.x == 0) {
        float t = red[0] + red[1] + red[2] + red[3];
        clsinv[b] = 1.0f / fmaxf(sqrtf(t), 1e-12f);
    }
}

// K1: fused unmasked scores + softmax + attn write + cosine sim.
// grid (12, B_), block 256. Each block: 48 patches of batch b.
// Each wave: 4 patches (one per 16-lane row), lanes k-slice D with interleaved
// float4 mapping d = j*64 + lr*4  (bank-conflict-free LDS reads, 4-row broadcast).
__global__ __launch_bounds__(256) void k1_score(const float* __restrict__ x,
                                                const float* __restrict__ gw,
                                                const float* __restrict__ clsinv,
                                                float* __restrict__ sim,
                                                float* __restrict__ attn) {
    __shared__ __align__(16) float wl[18 * 772];   // rows 0..16 = gw^T, row 17 = cls
    int tid = threadIdx.x;
    int b = blockIdx.y;
    int chunk = blockIdx.x;

    for (int i = tid; i < D_ * G_; i += 256) {
        int d = i / G_;
        int g = i - d * G_;
        wl[g * 772 + d] = gw[i];            // gw is (D,G) row-major
    }
    for (int i = tid; i < D_; i += 256)
        wl[17 * 772 + i] = x[(size_t)b * NTOK * D_ + i];
    __syncthreads();

    float cinv = clsinv[b];
    int wave = tid >> 6, lane = tid & 63;
    int row = lane >> 4, lr = lane & 15;

    for (int it = 0; it < 3; ++it) {
        int p = chunk * 48 + it * 16 + wave * 4 + row;
        const float4* xp = (const float4*)(x + ((size_t)(b * NTOK + 1 + p)) * D_);
        float4 r[12];
        #pragma unroll
        for (int j = 0; j < 12; ++j) r[j] = xp[j * 16 + lr];

        float s[19];
        for (int g = 0; g < 18; ++g) {
            const float4* wr = (const float4*)(wl + g * 772);
            float a0 = 0.f, a1 = 0.f;
            #pragma unroll
            for (int j = 0; j < 12; j += 2) {
                a0 += dot4(r[j],     wr[j * 16 + lr]);
                a1 += dot4(r[j + 1], wr[(j + 1) * 16 + lr]);
            }
            s[g] = a0 + a1;
        }
        {   // patch sumsq
            float a0 = 0.f, a1 = 0.f;
            #pragma unroll
            for (int j = 0; j < 12; j += 2) {
                a0 += dot4(r[j], r[j]);
                a1 += dot4(r[j + 1], r[j + 1]);
            }
            s[18] = a0 + a1;
        }
        // reduce within 16-lane rows (xor 1,2,4,8) — all lanes get full sums
        #pragma unroll
        for (int off = 1; off < 16; off <<= 1) {
            #pragma unroll
            for (int i = 0; i < 19; ++i) s[i] += __shfl_xor(s[i], off, 16);
        }
        // cosine sim vs cls
        float pn = sqrtf(s[18]);
        float sv = s[17] * cinv / fmaxf(pn, 1e-12f);
        if (lr == 0) sim[(size_t)b * P_ + p] = sv;
        // softmax over the 17 group scores (unmasked): attn = softmax(s * 10)
        float m = s[0];
        #pragma unroll
        for (int g = 1; g < 17; ++g) m = fmaxf(m, s[g]);
        float e[17];
        float tot = 0.f;
        #pragma unroll
        for (int g = 0; g < 17; ++g) {
            e[g] = __expf((s[g] - m) * INV_TEMP);
            tot += e[g];
        }
        float inv = 1.0f / tot;
        float* ap = attn + ((size_t)b * G_) * P_ + p;
        #pragma unroll
        for (int g = 0; g < 16; ++g)
            if (lr == g) ap[(size_t)g * P_] = e[g] * inv;   // lanes 0..15 -> groups 0..15
        if (lr == 15) ap[(size_t)16 * P_] = e[16] * inv;    // lane 15 also writes group 16
    }
}

// K2: per batch (1 wave): select 10 smallest sims (ties -> lower index, matches
// top_k(-sim)), write mask, overwrite occluded attn columns with 1/17.
__global__ __launch_bounds__(64) void k2_occl(const float* __restrict__ sim,
                                              float* __restrict__ mask,
                                              float* __restrict__ attn) {
    int b = blockIdx.x, lane = threadIdx.x;
    int base = lane * 9;                      // 64*9 == 576
    float v[9];
    bool occ[9];
    #pragma unroll
    for (int j = 0; j < 9; ++j) {
        v[j] = sim[(size_t)b * P_ + base + j];
        occ[j] = false;
    }
    int wins[KOCC];
    for (int t = 0; t < KOCC; ++t) {
        float mv = 3.0e38f;
        int mi = 1 << 30;
        #pragma unroll
        for (int j = 0; j < 9; ++j) {
            if (v[j] < mv) { mv = v[j]; mi = base + j; }   // strict < : lowest idx on tie
        }
        #pragma unroll
        for (int off = 1; off < 64; off <<= 1) {
            float ov = __shfl_xor(mv, off, 64);
            int oi = __shfl_xor(mi, off, 64);
            if (ov < mv || (ov == mv && oi < mi)) { mv = ov; mi = oi; }
        }
        wins[t] = mi;                          // lane-uniform
        int loc = mi - base;
        if (loc >= 0 && loc < 9) { v[loc] = 3.0e38f; occ[loc] = true; }
    }
    #pragma unroll
    for (int j = 0; j < 9; ++j)
        mask[(size_t)b * P_ + base + j] = occ[j] ? 0.0f : 1.0f;
    const float u = 1.0f / 17.0f;
    for (int t = 0; t < KOCC; ++t) {
        if (lane < G_) attn[((size_t)b * G_ + lane) * P_ + wins[t]] = u;
    }
}

// K3: group features. grid (2 p-halves, 3 d-chunks, B_), block 256.
// Thread owns one d; attn tile + mask staged in LDS; atomicAdd into zeroed feats.
__global__ __launch_bounds__(256) void k3_gf(const float* __restrict__ x,
                                             const float* __restrict__ attn,
                                             const float* __restrict__ mask,
                                             float* __restrict__ feats) {
    __shared__ __align__(16) float al[17 * 288];
    __shared__ __align__(16) float ml[288];
    int tid = threadIdx.x;
    int ph = blockIdx.x;          // 0..1
    int dc = blockIdx.y;          // 0..2
    int b  = blockIdx.z;
    int p0 = ph * 288;

    for (int i = tid; i < 17 * 288; i += 256) {
        int g = i / 288;
        int pp = i - g * 288;
        al[i] = attn[((size_t)b * G_ + g) * P_ + p0 + pp];
    }
    for (int i = tid; i < 288; i += 256)
        ml[i] = mask[(size_t)b * P_ + p0 + i];
    __syncthreads();

    int d = dc * 256 + tid;
    const float* xb = x + ((size_t)(b * NTOK) + 1 + p0) * D_ + d;
    float acc[17];
    #pragma unroll
    for (int g = 0; g < 17; ++g) acc[g] = 0.f;

    for (int pp = 0; pp < 288; pp += 4) {
        float xv0 = xb[(size_t)(pp + 0) * D_] * ml[pp + 0];
        float xv1 = xb[(size_t)(pp + 1) * D_] * ml[pp + 1];
        float xv2 = xb[(size_t)(pp + 2) * D_] * ml[pp + 2];
        float xv3 = xb[(size_t)(pp + 3) * D_] * ml[pp + 3];
        #pragma unroll
        for (int g = 0; g < 17; ++g) {
            float4 a4 = *(const float4*)&al[g * 288 + pp];
            acc[g] = fmaf(a4.x, xv0, acc[g]);
            acc[g] = fmaf(a4.y, xv1, acc[g]);
            acc[g] = fmaf(a4.z, xv2, acc[g]);
            acc[g] = fmaf(a4.w, xv3, acc[g]);
        }
    }
    float* fb = feats + ((size_t)(b * 18) + 1) * D_ + d;
    #pragma unroll
    for (int g = 0; g < 17; ++g) atomicAdd(fb + (size_t)g * D_, acc[g]);
}

extern "C" void kernel_launch(void* const* d_in, const int* in_sizes, int n_in,
                              void* d_out, int out_size, void* d_ws, size_t ws_size,
                              hipStream_t stream) {
    const float* x  = (const float*)d_in[0];
    const float* gw = (const float*)d_in[1];
    float* feats = (float*)d_out;                               // B*18*D
    float* attn  = (float*)d_out + (size_t)B_ * 18 * D_;        // B*17*P
    float* sim    = (float*)d_ws;
    float* mask   = (float*)d_ws + (size_t)B_ * P_;
    float* clsinv = (float*)d_ws + (size_t)2 * B_ * P_;

    k0_cls<<<B_, 256, 0, stream>>>(x, feats, clsinv);
    k1_score<<<dim3(12, B_), 256, 0, stream>>>(x, gw, clsinv, sim, attn);
    k2_occl<<<B_, 64, 0, stream>>>(sim, mask, attn);
    k3_gf<<<dim3(2, 3, B_), 256, 0, stream>>>(x, attn, mask, feats);
}